// Round 4
// baseline (339.283 us; speedup 1.0000x reference)
//
#include <hip/hip_runtime.h>
#include <stdint.h>

#define NB    32
#define CIN   64
#define HW    56
#define OHW   57
#define LL    3249
#define PATCH 256
#define NCENT 512
#define OC    128
#define NROWS (NB*LL)          // 103968
#define NROWS_PAD 104064       // 813*128
#define PL    (PATCH*LL)       // 831744
#define CT    32               // center chunk
#define NCH   (NCENT/CT)       // 16

typedef __attribute__((ext_vector_type(8))) short short8;      // bf16x8 MFMA frag
typedef __attribute__((ext_vector_type(4))) float f32x4;
typedef __attribute__((ext_vector_type(4))) int   int4v;
typedef int int4u __attribute__((ext_vector_type(4), aligned(4)));
typedef __attribute__((ext_vector_type(4))) unsigned short ushort4v;

// ---------------- ws layout ----------------
constexpr size_t OFF_C2   = 0;
constexpr size_t OFF_X2   = 4096;
constexpr size_t OFF_CBF  = OFF_X2 + (size_t)NROWS_PAD*4;
constexpr size_t OFF_CTBF = OFF_CBF + (size_t)NCENT*PATCH*2;
constexpr size_t OFF_WBF  = OFF_CTBF + (size_t)PATCH*NCENT*2;
constexpr size_t OFF_FLAT = OFF_WBF + (size_t)OC*PATCH*2;
constexpr size_t OFF_FBM  = OFF_FLAT + (size_t)NROWS_PAD*PATCH*2;

__device__ __forceinline__ short f2bf(float f) {
    union { float f; uint32_t u; } v; v.f = f;
    uint32_t r = (v.u + 0x7FFFu + ((v.u >> 16) & 1u)) >> 16;
    return (short)r;
}
__device__ __forceinline__ float bf2f(uint16_t h) {
    union { uint32_t u; float f; } v; v.u = ((uint32_t)h) << 16;
    return v.f;
}
__device__ __forceinline__ void gload16(const void* g, void* l) {
    __builtin_amdgcn_global_load_lds(
        (const __attribute__((address_space(1))) unsigned int*)g,
        (__attribute__((address_space(3))) unsigned int*)l, 16, 0, 0);
}

// ---------------- K0a: centers -> cbf (swz), ctbf (T, swz key m&3), c2 ----------------
__global__ __launch_bounds__(256)
void k0a_centers(const float* __restrict__ centers, uint16_t* __restrict__ cbf,
                 uint16_t* __restrict__ ctbf, float* __restrict__ c2) {
    __shared__ float red[4];
    int c = blockIdx.x;            // 0..511 center
    int k = threadIdx.x;           // 0..255 patch
    float v = centers[c*PATCH + k];
    cbf[c*PATCH + (k ^ ((c & 7) << 3))] = (uint16_t)f2bf(v);
    ctbf[k*NCENT + (c ^ ((k & 3) << 3))] = (uint16_t)f2bf(v);   // key m&3: 32-slice closed
    float s = v*v;
    s += __shfl_xor(s, 1);  s += __shfl_xor(s, 2);  s += __shfl_xor(s, 4);
    s += __shfl_xor(s, 8);  s += __shfl_xor(s, 16); s += __shfl_xor(s, 32);
    int w = threadIdx.x >> 6;
    if ((threadIdx.x & 63) == 0) red[w] = s;
    __syncthreads();
    if (threadIdx.x == 0) c2[c] = red[0] + red[1] + red[2] + red[3];
}

// ---------------- K0w: weight -> wbf (swz) ----------------
__global__ __launch_bounds__(256)
void k0w_weight(const float* __restrict__ weight, uint16_t* __restrict__ wbf) {
    int o = blockIdx.x, p = threadIdx.x;
    wbf[o*PATCH + (p ^ ((o & 7) << 3))] = (uint16_t)f2bf(weight[o*PATCH + p]);
}

// ---------------- K0b: x -> flat bf16 (swz) + x2 ----------------
__global__ __launch_bounds__(256)
void k0b_flat(const float* __restrict__ x, uint16_t* __restrict__ flat,
              float* __restrict__ x2) {
    int tid = threadIdx.x;
    int w = tid >> 6, lane = tid & 63;
    for (int pp = 0; pp < 8; ++pp) {
        int n = blockIdx.x*32 + pp*4 + w;
        int b = n / LL;
        int rr = n - b*LL;
        int k0 = lane*4;
        float s = 0.f;
        ushort4v pk;
#pragma unroll
        for (int e = 0; e < 4; ++e) {
            int k = k0 + e;
            float val = 0.f;
            if (n < NROWS) {
                int o = rr*PATCH + k;
                int p = o / LL; int l = o - p*LL;
                int cc = p >> 2, ki = (p >> 1) & 1, kj = p & 1;
                int i = l / OHW; int j = l - i*OHW;
                int y = i + ki - 1, xx = j + kj - 1;
                if ((unsigned)y < HW && (unsigned)xx < HW)
                    val = x[((b*CIN + cc)*HW + y)*HW + xx];
            }
            pk[e] = (unsigned short)f2bf(val);
            s += val*val;
        }
        *(ushort4v*)(flat + (size_t)n*PATCH + (k0 ^ ((n & 7) << 3))) = pk;
        s += __shfl_xor(s, 1);  s += __shfl_xor(s, 2);  s += __shfl_xor(s, 4);
        s += __shfl_xor(s, 8);  s += __shfl_xor(s, 16); s += __shfl_xor(s, 32);
        if (lane == 0) x2[n] = s;
    }
}

// ---------------- K12: fused scores + softmax + PV + final + mask -> fbm ----------------
// 128 rows/block, 16 chunks of 32 centers. A in registers, den in registers.
__global__ __launch_bounds__(256, 1)
void k12_fused(const uint16_t* __restrict__ flat, const uint16_t* __restrict__ cbf,
               const uint16_t* __restrict__ ctbf, const float* __restrict__ x2g,
               const float* __restrict__ c2g, const float* __restrict__ temp_p,
               uint16_t* __restrict__ fbm) {
    __shared__ __align__(16) char lds[58368];
    char* sB0 = lds;                       // 2 x 16384 (32 c-rows x 512 B)
    char* sB1 = lds + 16384;
    char* sV  = lds + 32768;               // 16384 (256 m-rows x 64 B)
    uint16_t* sP = (uint16_t*)(lds + 49152);   // 8192 (128 n x 32 c bf16, swz)
    float* sDen  = (float*)(lds + 57344);      // 128 x 2 f32

    const int tid = threadIdx.x;
    const int mt = blockIdx.x;
    const int lane = tid & 63;
    const int w = tid >> 6;
    const int wr = w >> 1, wc = w & 1;
    const int l15 = lane & 15, l4 = lane >> 4;
    const float temp = temp_p[0];

    const uint16_t* fr = flat + (size_t)mt*128*PATCH;

    auto stage_B = [&](char* dst, int cc) {
        const char* src = (const char*)cbf + (size_t)(cc*CT)*512;
#pragma unroll
        for (int j = 0; j < 4; ++j) {
            int idx = j*256 + tid;
            gload16(src + idx*16, dst + idx*16);
        }
    };
    auto stage_V = [&](int cc) {
        const char* src = (const char*)ctbf + cc*64;
#pragma unroll
        for (int j = 0; j < 4; ++j) {
            int idx = j*256 + tid;
            int m = idx >> 2, sub = idx & 3;
            gload16(src + (size_t)m*1024 + sub*16, sV + idx*16);
        }
    };

    // prologue: stage chunk0 B; load x2; load A-frags from global (pre-swizzled)
    stage_B(sB0, 0);

    f32x4 x2r[4];
#pragma unroll
    for (int rf = 0; rf < 4; ++rf)
#pragma unroll
        for (int rr = 0; rr < 4; ++rr)
            x2r[rf][rr] = x2g[mt*128 + wr*64 + rf*16 + l4*4 + rr];

    short8 areg[4][8];
#pragma unroll
    for (int rf = 0; rf < 4; ++rf) {
        int row = wr*64 + rf*16 + l15;
#pragma unroll
        for (int ks = 0; ks < 8; ++ks) {
            int ko = (ks*32 + l4*8) ^ ((row & 7) << 3);
            areg[rf][ks] = *(const short8*)(fr + row*PATCH + ko);
        }
    }

    f32x4 Tacc[4][8];
#pragma unroll
    for (int i = 0; i < 4; ++i)
#pragma unroll
        for (int j = 0; j < 8; ++j) Tacc[i][j] = (f32x4)0.f;
    f32x4 denreg[4];
#pragma unroll
    for (int i = 0; i < 4; ++i) denreg[i] = (f32x4)0.f;

    __syncthreads();   // sB0 (and A/x2 loads) complete

    for (int cc = 0; cc < NCH; ++cc) {
        char* Bcur = (cc & 1) ? sB1 : sB0;
        char* Bnext = (cc & 1) ? sB0 : sB1;
        stage_V(cc);                          // consumed after barrier (a)
        if (cc < NCH-1) stage_B(Bnext, cc + 1);
        float c2v = c2g[cc*CT + wc*16 + l15];

        // ---- scores: S[128][32] (this wave: rows wr*64.., c = wc*16+l15)
        f32x4 s[4];
#pragma unroll
        for (int i = 0; i < 4; ++i) s[i] = (f32x4)0.f;
        {
            int rowb = wc*16 + l15;
#pragma unroll
            for (int ks = 0; ks < 8; ++ks) {
                int byte = rowb*512 + ((ks*64 + l4*16) ^ ((rowb & 7) << 4));
                short8 bfr = *(const short8*)(Bcur + byte);
#pragma unroll
                for (int rf = 0; rf < 4; ++rf)
                    s[rf] = __builtin_amdgcn_mfma_f32_16x16x32_bf16(
                        areg[rf][ks], bfr, s[rf], 0, 0, 0);
            }
        }
        // ---- exp + den accum + bounce P to LDS (swz key n&3)
#pragma unroll
        for (int rf = 0; rf < 4; ++rf) {
#pragma unroll
            for (int rr = 0; rr < 4; ++rr) {
                int n = wr*64 + rf*16 + l4*4 + rr;
                float sv = x2r[rf][rr] + c2v - 2.f*s[rf][rr];
                float pv = __expf(-temp * sqrtf(fmaxf(sv, 0.f)));
                denreg[rf][rr] += pv;
                int cl = wc*16 + l15;
                sP[n*32 + (cl ^ ((n & 3) << 3))] = (uint16_t)f2bf(pv);
            }
        }
        __syncthreads();   // (a) sP + sV ready

        // ---- PV: Tacc += P[128][32] @ V[32][256]
        short8 ap[4];
#pragma unroll
        for (int rf = 0; rf < 4; ++rf) {
            int n = wr*64 + rf*16 + l15;
            int byte = n*64 + ((l4*16) ^ ((n & 3) << 4));
            ap[rf] = *(const short8*)((const char*)sP + byte);
        }
#pragma unroll
        for (int cfm = 0; cfm < 8; ++cfm) {
            int m = wc*128 + cfm*16 + l15;
            int byte = m*64 + ((l4*16) ^ ((m & 3) << 4));
            short8 bv = *(const short8*)(sV + byte);
#pragma unroll
            for (int rf = 0; rf < 4; ++rf)
                Tacc[rf][cfm] = __builtin_amdgcn_mfma_f32_16x16x32_bf16(
                    ap[rf], bv, Tacc[rf][cfm], 0, 0, 0);
        }
        __syncthreads();   // (b) sP/sV free for next chunk
    }

    // ---- den reduce: over l15 (16 lanes) then cross-wc via LDS
#pragma unroll
    for (int rf = 0; rf < 4; ++rf)
#pragma unroll
        for (int rr = 0; rr < 4; ++rr) {
            float v = denreg[rf][rr];
            v += __shfl_xor(v, 1); v += __shfl_xor(v, 2);
            v += __shfl_xor(v, 4); v += __shfl_xor(v, 8);
            if (l15 == 0) {
                int n = wr*64 + rf*16 + l4*4 + rr;
                sDen[n*2 + wc] = v;
            }
        }
    __syncthreads();

    // ---- final = (temp*T/den + flat)/(temp+1), fold/conv mask, direct stores
    const float inv = 1.f / (temp + 1.f);
#pragma unroll
    for (int rf = 0; rf < 4; ++rf) {
#pragma unroll
        for (int rr = 0; rr < 4; ++rr) {
            int nl = wr*64 + rf*16 + l4*4 + rr;
            int n = mt*128 + nl;
            if (n >= NROWS) continue;
            float den = sDen[nl*2] + sDen[nl*2 + 1];
            float ts = temp / den;
            int b = n / LL;
            int rrow = n - b*LL;
#pragma unroll
            for (int cfm = 0; cfm < 8; ++cfm) {
                int m = wc*128 + cfm*16 + l15;
                float fl = bf2f(fr[nl*PATCH + (m ^ ((nl & 7) << 3))]);
                float fin = (ts * Tacc[rf][cfm][rr] + fl) * inv;
                int o = rrow*PATCH + m;
                int p = o / LL; int l = o - p*LL;
                int ii = l / OHW; int jj = l - ii*OHW;
                int ki = (p >> 1) & 1, kj = p & 1;
                bool bad = (ii == 0 && ki == 0) || (ii == 56 && ki == 1) ||
                           (jj == 0 && kj == 0) || (jj == 56 && kj == 1);
                fbm[(size_t)n*PATCH + m] = (uint16_t)f2bf(bad ? 0.f : fin);
            }
        }
    }
}

// ---------------- K4: conv GEMM: out[oc][l] = W @ fbm^T + bias ----------------
__global__ __launch_bounds__(256, 2)
void k4_conv(const uint16_t* __restrict__ wbf, const uint16_t* __restrict__ fbm,
             const float* __restrict__ bias, float* __restrict__ out) {
    __shared__ __align__(16) char lds[2][32768];
    const int tid = threadIdx.x;
    const int lt = blockIdx.x;     // l-tile 0..25
    const int bb = blockIdx.y;     // batch
    const int w = tid >> 6, lane = tid & 63;
    const int wr = w >> 1, wc = w & 1;
    const int l15 = lane & 15, l4 = lane >> 4;

    auto stageA = [&](int buf, int kt) {
        const char* srcA = (const char*)wbf + kt*128;
        char* dA = lds[buf];
#pragma unroll
        for (int i = 0; i < 4; ++i) {
            int c = (w*4 + i)*64 + lane;
            gload16(srcA + (size_t)(c >> 3)*512 + (c & 7)*16, dA + (w*4 + i)*1024);
        }
    };
    // B: transpose-stage fbm[p][l] -> sB[l][p] (swizzled)
    auto stageB = [&](int buf, int kt) {
        uint16_t* sB = (uint16_t*)(lds[buf] + 16384);
#pragma unroll
        for (int i = 0; i < 4; ++i) {
            int pl = lane;
            int l8 = i*4 + w;
            const uint16_t* g = fbm + (size_t)bb*PL + (size_t)(kt*64 + pl)*LL + lt*128 + l8*8;
#pragma unroll
            for (int e = 0; e < 8; ++e) {
                uint16_t val = g[e];
                int llocal = l8*8 + e;
                sB[llocal*64 + (pl ^ (e << 3))] = val;
            }
        }
    };

    f32x4 acc[4][4];
#pragma unroll
    for (int i = 0; i < 4; ++i)
#pragma unroll
        for (int j = 0; j < 4; ++j) acc[i][j] = (f32x4)0.f;

    stageA(0, 0); stageB(0, 0);
    for (int kt = 0; kt < 4; ++kt) {
        __syncthreads();
        if (kt < 3) { stageA((kt + 1) & 1, kt + 1); stageB((kt + 1) & 1, kt + 1); }
        const char* A = lds[kt & 1];
        const char* B = lds[kt & 1] + 16384;
#pragma unroll
        for (int ks = 0; ks < 2; ++ks) {
            short8 af[4], bfm[4];
#pragma unroll
            for (int rf = 0; rf < 4; ++rf) {
                int row = wr*64 + rf*16 + l15;
                int byte = row*128 + ((ks*64 + l4*16) ^ ((row & 7) << 4));
                af[rf] = *(const short8*)(A + byte);
            }
#pragma unroll
            for (int cf = 0; cf < 4; ++cf) {
                int row = wc*64 + cf*16 + l15;
                int byte = row*128 + ((ks*64 + l4*16) ^ ((row & 7) << 4));
                bfm[cf] = *(const short8*)(B + byte);
            }
#pragma unroll
            for (int rf = 0; rf < 4; ++rf)
#pragma unroll
                for (int cf = 0; cf < 4; ++cf)
                    acc[rf][cf] = __builtin_amdgcn_mfma_f32_16x16x32_bf16(
                        af[rf], bfm[cf], acc[rf][cf], 0, 0, 0);
        }
    }

    __syncthreads();
    float* Ol = (float*)lds;
    float bv[4][4];
#pragma unroll
    for (int rf = 0; rf < 4; ++rf)
#pragma unroll
        for (int rr = 0; rr < 4; ++rr)
            bv[rf][rr] = bias[wr*64 + rf*16 + l4*4 + rr];
#pragma unroll
    for (int rf = 0; rf < 4; ++rf)
#pragma unroll
        for (int cf = 0; cf < 4; ++cf)
#pragma unroll
            for (int rr = 0; rr < 4; ++rr) {
                int row = wr*64 + rf*16 + l4*4 + rr;
                int col = wc*64 + cf*16 + l15;
                Ol[row*128 + col] = acc[rf][cf][rr] + bv[rf][rr];
            }
    __syncthreads();
    if (lt < 25) {
#pragma unroll
        for (int i = 0; i < 16; ++i) {
            int c = i*256 + tid;
            int row = c >> 5, sub = c & 31;
            int4u v = *(const int4u*)((const char*)lds + c*16);
            *(int4u*)((char*)out + ((size_t)(bb*OC + row)*LL + lt*128 + sub*4)*4) = v;
        }
    } else {
#pragma unroll
        for (int i = 0; i < 16; ++i) {
            int c = i*256 + tid;
            int row = c >> 5, sub = c & 31;
            const float* vp = (const float*)((const char*)lds + c*16);
#pragma unroll
            for (int e = 0; e < 4; ++e) {
                int l = lt*128 + sub*4 + e;
                if (l < LL) out[(size_t)(bb*OC + row)*LL + l] = vp[e];
            }
        }
    }
}

extern "C" void kernel_launch(void* const* d_in, const int* in_sizes, int n_in,
                              void* d_out, int out_size, void* d_ws, size_t ws_size,
                              hipStream_t stream) {
    const float* x       = (const float*)d_in[0];
    const float* weight  = (const float*)d_in[1];
    const float* bias    = (const float*)d_in[2];
    const float* centers = (const float*)d_in[3];
    const float* temp    = (const float*)d_in[4];
    float* out = (float*)d_out;

    char* ws = (char*)d_ws;
    float*    c2   = (float*)(ws + OFF_C2);
    float*    x2   = (float*)(ws + OFF_X2);
    uint16_t* cbf  = (uint16_t*)(ws + OFF_CBF);
    uint16_t* ctbf = (uint16_t*)(ws + OFF_CTBF);
    uint16_t* wbf  = (uint16_t*)(ws + OFF_WBF);
    uint16_t* flat = (uint16_t*)(ws + OFF_FLAT);
    uint16_t* fbm  = (uint16_t*)(ws + OFF_FBM);

    k0a_centers<<<NCENT, 256, 0, stream>>>(centers, cbf, ctbf, c2);
    k0w_weight<<<OC, 256, 0, stream>>>(weight, wbf);
    k0b_flat<<<NROWS_PAD/32, 256, 0, stream>>>(x, flat, x2);
    k12_fused<<<NROWS_PAD/128, 256, 0, stream>>>(flat, cbf, ctbf, x2, c2, temp, fbm);
    k4_conv<<<dim3(26, NB), 256, 0, stream>>>(wbf, fbm, bias, out);
}